// Round 1
// baseline (4224.146 us; speedup 1.0000x reference)
//
#include <hip/hip_runtime.h>

#define D 128

// ---------------------------------------------------------------------------
// Scatter: agg[dst] += w * h[src], 32 lanes (float4 each) per edge.
// ---------------------------------------------------------------------------
__global__ __launch_bounds__(256) void scatter_kernel(
    const float* __restrict__ h, const int* __restrict__ src,
    const int* __restrict__ dst, const float* __restrict__ ew,
    float* __restrict__ agg, int E)
{
    int t = blockIdx.x * 256 + threadIdx.x;
    int e = t >> 5;
    if (e >= E) return;
    int lane4 = (t & 31) * 4;
    int s = src[e];
    int d = dst[e];
    float w = ew[e];
    float4 v = *(const float4*)(h + (size_t)s * D + lane4);
    float* o = agg + (size_t)d * D + lane4;
    unsafeAtomicAdd(o + 0, v.x * w);
    unsafeAtomicAdd(o + 1, v.y * w);
    unsafeAtomicAdd(o + 2, v.z * w);
    unsafeAtomicAdd(o + 3, v.w * w);
}

// ---------------------------------------------------------------------------
// Fused GEMM: out = agg @ Wrel + b + h @ Wroot, optional relu.
// Block: 256 threads, 64 rows x 128 cols. Thread: 8 rows x 4 cols.
// a_s layout per row: [agg row (128) | h row (128)] -> K=256.
// ---------------------------------------------------------------------------
#define FMA4(ACC, AV, W0, W1, W2, W3)                    \
    do {                                                 \
        ACC.x = fmaf(AV.x, W0.x, ACC.x);                 \
        ACC.y = fmaf(AV.x, W0.y, ACC.y);                 \
        ACC.z = fmaf(AV.x, W0.z, ACC.z);                 \
        ACC.w = fmaf(AV.x, W0.w, ACC.w);                 \
        ACC.x = fmaf(AV.y, W1.x, ACC.x);                 \
        ACC.y = fmaf(AV.y, W1.y, ACC.y);                 \
        ACC.z = fmaf(AV.y, W1.z, ACC.z);                 \
        ACC.w = fmaf(AV.y, W1.w, ACC.w);                 \
        ACC.x = fmaf(AV.z, W2.x, ACC.x);                 \
        ACC.y = fmaf(AV.z, W2.y, ACC.y);                 \
        ACC.z = fmaf(AV.z, W2.z, ACC.z);                 \
        ACC.w = fmaf(AV.z, W2.w, ACC.w);                 \
        ACC.x = fmaf(AV.w, W3.x, ACC.x);                 \
        ACC.y = fmaf(AV.w, W3.y, ACC.y);                 \
        ACC.z = fmaf(AV.w, W3.z, ACC.z);                 \
        ACC.w = fmaf(AV.w, W3.w, ACC.w);                 \
    } while (0)

__global__ __launch_bounds__(256, 2) void gemm_fused(
    const float* __restrict__ agg, const float* __restrict__ h,
    const float* __restrict__ Wrel, const float* __restrict__ bias,
    const float* __restrict__ Wroot, float* __restrict__ out,
    int N, int relu)
{
    __shared__ float a_s[64 * 256];
    int tid = threadIdx.x;
    int row0 = blockIdx.x * 64;

    // Stage 64 rows of [agg | h] into LDS. Each thread: 16 float4 loads.
    #pragma unroll
    for (int j = 0; j < 16; ++j) {
        int f = j * 256 + tid;   // float4 index in [0, 4096)
        int r = f >> 6;          // row 0..63
        int q = f & 63;          // quad 0..63 (0-31 agg, 32-63 h)
        int gr = row0 + r;
        float4 v = make_float4(0.f, 0.f, 0.f, 0.f);
        if (gr < N) {
            const float* p = (q < 32) ? (agg + (size_t)gr * D + q * 4)
                                      : (h + (size_t)gr * D + (q - 32) * 4);
            v = *(const float4*)p;
        }
        *(float4*)&a_s[r * 256 + q * 4] = v;
    }
    __syncthreads();

    int colg = tid & 31;
    int rowg = tid >> 5;
    int c0 = colg * 4;

    float4 acc[8];
    #pragma unroll
    for (int i = 0; i < 8; ++i) acc[i] = make_float4(0.f, 0.f, 0.f, 0.f);

    // Pass 1: agg @ Wrel  (k = 0..127 of a_s)
    #pragma unroll 2
    for (int k = 0; k < 128; k += 4) {
        float4 w0 = *(const float4*)(Wrel + (size_t)(k + 0) * D + c0);
        float4 w1 = *(const float4*)(Wrel + (size_t)(k + 1) * D + c0);
        float4 w2 = *(const float4*)(Wrel + (size_t)(k + 2) * D + c0);
        float4 w3 = *(const float4*)(Wrel + (size_t)(k + 3) * D + c0);
        #pragma unroll
        for (int i = 0; i < 8; ++i) {
            float4 av = *(const float4*)&a_s[(rowg * 8 + i) * 256 + k];
            FMA4(acc[i], av, w0, w1, w2, w3);
        }
    }
    // Pass 2: h @ Wroot  (k = 128..255 of a_s)
    #pragma unroll 2
    for (int k = 0; k < 128; k += 4) {
        float4 w0 = *(const float4*)(Wroot + (size_t)(k + 0) * D + c0);
        float4 w1 = *(const float4*)(Wroot + (size_t)(k + 1) * D + c0);
        float4 w2 = *(const float4*)(Wroot + (size_t)(k + 2) * D + c0);
        float4 w3 = *(const float4*)(Wroot + (size_t)(k + 3) * D + c0);
        #pragma unroll
        for (int i = 0; i < 8; ++i) {
            float4 av = *(const float4*)&a_s[(rowg * 8 + i) * 256 + 128 + k];
            FMA4(acc[i], av, w0, w1, w2, w3);
        }
    }

    float4 bv = *(const float4*)(bias + c0);
    #pragma unroll
    for (int i = 0; i < 8; ++i) {
        int gr = row0 + rowg * 8 + i;
        if (gr < N) {
            float4 o = acc[i];
            o.x += bv.x; o.y += bv.y; o.z += bv.z; o.w += bv.w;
            if (relu) {
                o.x = fmaxf(o.x, 0.f); o.y = fmaxf(o.y, 0.f);
                o.z = fmaxf(o.z, 0.f); o.w = fmaxf(o.w, 0.f);
            }
            *(float4*)(out + (size_t)gr * D + c0) = o;
        }
    }
}

// ---------------------------------------------------------------------------
extern "C" void kernel_launch(void* const* d_in, const int* in_sizes, int n_in,
                              void* d_out, int out_size, void* d_ws, size_t ws_size,
                              hipStream_t stream)
{
    const float* x     = (const float*)d_in[0];
    const int*   ei    = (const int*)d_in[1];
    const float* ew    = (const float*)d_in[2];
    const float* Wrel  = (const float*)d_in[3];
    const float* brel  = (const float*)d_in[4];
    const float* Wroot = (const float*)d_in[5];
    float* out = (float*)d_out;

    int N = in_sizes[0] / D;
    int E = in_sizes[2];
    const int* src = ei;
    const int* dst = ei + E;

    float* agg = (float*)d_ws;                 // N*D
    float* h2  = agg + (size_t)N * D;          // N*D

    size_t aggBytes = (size_t)N * D * sizeof(float);
    dim3 sblk(256), sgrd((unsigned)(((size_t)E * 32 + 255) / 256));
    dim3 gblk(256), ggrd((N + 63) / 64);

    // Layer 0: x -> out (relu)
    hipMemsetAsync(agg, 0, aggBytes, stream);
    scatter_kernel<<<sgrd, sblk, 0, stream>>>(x, src, dst, ew, agg, E);
    gemm_fused<<<ggrd, gblk, 0, stream>>>(agg, x, Wrel, brel, Wroot, out, N, 1);

    // Layer 1: out -> h2 (relu)
    hipMemsetAsync(agg, 0, aggBytes, stream);
    scatter_kernel<<<sgrd, sblk, 0, stream>>>(out, src, dst, ew, agg, E);
    gemm_fused<<<ggrd, gblk, 0, stream>>>(agg, out, Wrel + 128 * 128, brel + 128,
                                          Wroot + 128 * 128, h2, N, 1);

    // Layer 2: h2 -> out (no relu)
    hipMemsetAsync(agg, 0, aggBytes, stream);
    scatter_kernel<<<sgrd, sblk, 0, stream>>>(h2, src, dst, ew, agg, E);
    gemm_fused<<<ggrd, gblk, 0, stream>>>(agg, h2, Wrel + 2 * 128 * 128, brel + 2 * 128,
                                          Wroot + 2 * 128 * 128, out, N, 0);
}

// Round 2
// 551.080 us; speedup vs baseline: 7.6652x; 7.6652x over previous
//
#include <hip/hip_runtime.h>

#define D 128

// ---------------------------------------------------------------------------
// CSR build step 1: histogram of dst
// ---------------------------------------------------------------------------
__global__ __launch_bounds__(256) void hist_kernel(
    const int* __restrict__ dst, int* __restrict__ counts, int E)
{
    int e = blockIdx.x * 256 + threadIdx.x;
    if (e < E) atomicAdd(&counts[dst[e]], 1);
}

// ---------------------------------------------------------------------------
// CSR build step 2: exclusive scan of counts -> row_ptr (and cursor copy).
// Single block, 1024 threads, each handles a contiguous chunk.
// ---------------------------------------------------------------------------
__global__ __launch_bounds__(1024) void scan_kernel(
    const int* __restrict__ counts, int* __restrict__ row_ptr,
    int* __restrict__ cursor, int N, int E)
{
    __shared__ int part[1024];
    int t = threadIdx.x;
    int CH = (N + 1023) / 1024;
    int beg = t * CH;
    int end = min(beg + CH, N);

    int s = 0;
    for (int i = beg; i < end; ++i) s += counts[i];
    part[t] = s;
    __syncthreads();

    // inclusive scan over part (Hillis-Steele, read-all/write-all)
    for (int off = 1; off < 1024; off <<= 1) {
        int tmp = (t >= off) ? part[t - off] : 0;
        __syncthreads();
        part[t] += tmp;
        __syncthreads();
    }

    int run = part[t] - s;   // exclusive prefix for this chunk
    for (int i = beg; i < end; ++i) {
        row_ptr[i] = run;
        cursor[i]  = run;
        run += counts[i];
    }
    if (t == 0) row_ptr[N] = E;
}

// ---------------------------------------------------------------------------
// CSR build step 3: scatter (src, w) into dst-sorted order
// ---------------------------------------------------------------------------
__global__ __launch_bounds__(256) void scatter_csr_kernel(
    const int* __restrict__ src, const int* __restrict__ dst,
    const float* __restrict__ ew, int* __restrict__ cursor,
    int* __restrict__ ssrc, float* __restrict__ sw, int E)
{
    int e = blockIdx.x * 256 + threadIdx.x;
    if (e >= E) return;
    int d = dst[e];
    int pos = atomicAdd(&cursor[d], 1);
    ssrc[pos] = src[e];
    sw[pos]   = ew[e];
}

// ---------------------------------------------------------------------------
// Aggregation: one 64-lane wave per node. Lane holds float2 of the feature
// row. Edge (src,w) pairs loaded coalesced 64-at-a-time, broadcast via shfl.
// ---------------------------------------------------------------------------
__global__ __launch_bounds__(256) void gather_csr_kernel(
    const float* __restrict__ h, const int* __restrict__ ssrc,
    const float* __restrict__ sw, const int* __restrict__ row_ptr,
    float* __restrict__ agg, int N)
{
    int wave = (blockIdx.x * 256 + threadIdx.x) >> 6;
    int lane = threadIdx.x & 63;
    if (wave >= N) return;

    int beg = row_ptr[wave];
    int cnt = row_ptr[wave + 1] - beg;

    float2 acc0 = make_float2(0.f, 0.f);
    float2 acc1 = make_float2(0.f, 0.f);

    for (int base = 0; base < cnt; base += 64) {
        int k = base + lane;
        int sv = 0; float wv = 0.f;
        if (k < cnt) { sv = ssrc[beg + k]; wv = sw[beg + k]; }
        int m = min(64, cnt - base);
        int j = 0;
        for (; j + 1 < m; j += 2) {
            int   s0 = __shfl(sv, j);
            float w0 = __shfl(wv, j);
            int   s1 = __shfl(sv, j + 1);
            float w1 = __shfl(wv, j + 1);
            float2 v0 = *(const float2*)(h + (size_t)s0 * D + lane * 2);
            float2 v1 = *(const float2*)(h + (size_t)s1 * D + lane * 2);
            acc0.x = fmaf(w0, v0.x, acc0.x);
            acc0.y = fmaf(w0, v0.y, acc0.y);
            acc1.x = fmaf(w1, v1.x, acc1.x);
            acc1.y = fmaf(w1, v1.y, acc1.y);
        }
        if (j < m) {
            int   s0 = __shfl(sv, j);
            float w0 = __shfl(wv, j);
            float2 v0 = *(const float2*)(h + (size_t)s0 * D + lane * 2);
            acc0.x = fmaf(w0, v0.x, acc0.x);
            acc0.y = fmaf(w0, v0.y, acc0.y);
        }
    }
    acc0.x += acc1.x;
    acc0.y += acc1.y;
    *(float2*)(agg + (size_t)wave * D + lane * 2) = acc0;
}

// ---------------------------------------------------------------------------
// Fused GEMM: out = agg @ Wrel + b + h @ Wroot, optional relu.
// Block: 256 threads, 64 rows x 128 cols. Thread: 8 rows x 4 cols.
// ---------------------------------------------------------------------------
#define FMA4(ACC, AV, W0, W1, W2, W3)                    \
    do {                                                 \
        ACC.x = fmaf(AV.x, W0.x, ACC.x);                 \
        ACC.y = fmaf(AV.x, W0.y, ACC.y);                 \
        ACC.z = fmaf(AV.x, W0.z, ACC.z);                 \
        ACC.w = fmaf(AV.x, W0.w, ACC.w);                 \
        ACC.x = fmaf(AV.y, W1.x, ACC.x);                 \
        ACC.y = fmaf(AV.y, W1.y, ACC.y);                 \
        ACC.z = fmaf(AV.y, W1.z, ACC.z);                 \
        ACC.w = fmaf(AV.y, W1.w, ACC.w);                 \
        ACC.x = fmaf(AV.z, W2.x, ACC.x);                 \
        ACC.y = fmaf(AV.z, W2.y, ACC.y);                 \
        ACC.z = fmaf(AV.z, W2.z, ACC.z);                 \
        ACC.w = fmaf(AV.z, W2.w, ACC.w);                 \
        ACC.x = fmaf(AV.w, W3.x, ACC.x);                 \
        ACC.y = fmaf(AV.w, W3.y, ACC.y);                 \
        ACC.z = fmaf(AV.w, W3.z, ACC.z);                 \
        ACC.w = fmaf(AV.w, W3.w, ACC.w);                 \
    } while (0)

__global__ __launch_bounds__(256, 2) void gemm_fused(
    const float* __restrict__ agg, const float* __restrict__ h,
    const float* __restrict__ Wrel, const float* __restrict__ bias,
    const float* __restrict__ Wroot, float* __restrict__ out,
    int N, int relu)
{
    __shared__ float a_s[64 * 256];
    int tid = threadIdx.x;
    int row0 = blockIdx.x * 64;

    #pragma unroll
    for (int j = 0; j < 16; ++j) {
        int f = j * 256 + tid;
        int r = f >> 6;
        int q = f & 63;
        int gr = row0 + r;
        float4 v = make_float4(0.f, 0.f, 0.f, 0.f);
        if (gr < N) {
            const float* p = (q < 32) ? (agg + (size_t)gr * D + q * 4)
                                      : (h + (size_t)gr * D + (q - 32) * 4);
            v = *(const float4*)p;
        }
        *(float4*)&a_s[r * 256 + q * 4] = v;
    }
    __syncthreads();

    int colg = tid & 31;
    int rowg = tid >> 5;
    int c0 = colg * 4;

    float4 acc[8];
    #pragma unroll
    for (int i = 0; i < 8; ++i) acc[i] = make_float4(0.f, 0.f, 0.f, 0.f);

    #pragma unroll 2
    for (int k = 0; k < 128; k += 4) {
        float4 w0 = *(const float4*)(Wrel + (size_t)(k + 0) * D + c0);
        float4 w1 = *(const float4*)(Wrel + (size_t)(k + 1) * D + c0);
        float4 w2 = *(const float4*)(Wrel + (size_t)(k + 2) * D + c0);
        float4 w3 = *(const float4*)(Wrel + (size_t)(k + 3) * D + c0);
        #pragma unroll
        for (int i = 0; i < 8; ++i) {
            float4 av = *(const float4*)&a_s[(rowg * 8 + i) * 256 + k];
            FMA4(acc[i], av, w0, w1, w2, w3);
        }
    }
    #pragma unroll 2
    for (int k = 0; k < 128; k += 4) {
        float4 w0 = *(const float4*)(Wroot + (size_t)(k + 0) * D + c0);
        float4 w1 = *(const float4*)(Wroot + (size_t)(k + 1) * D + c0);
        float4 w2 = *(const float4*)(Wroot + (size_t)(k + 2) * D + c0);
        float4 w3 = *(const float4*)(Wroot + (size_t)(k + 3) * D + c0);
        #pragma unroll
        for (int i = 0; i < 8; ++i) {
            float4 av = *(const float4*)&a_s[(rowg * 8 + i) * 256 + 128 + k];
            FMA4(acc[i], av, w0, w1, w2, w3);
        }
    }

    float4 bv = *(const float4*)(bias + c0);
    #pragma unroll
    for (int i = 0; i < 8; ++i) {
        int gr = row0 + rowg * 8 + i;
        if (gr < N) {
            float4 o = acc[i];
            o.x += bv.x; o.y += bv.y; o.z += bv.z; o.w += bv.w;
            if (relu) {
                o.x = fmaxf(o.x, 0.f); o.y = fmaxf(o.y, 0.f);
                o.z = fmaxf(o.z, 0.f); o.w = fmaxf(o.w, 0.f);
            }
            *(float4*)(out + (size_t)gr * D + c0) = o;
        }
    }
}

// ---------------------------------------------------------------------------
extern "C" void kernel_launch(void* const* d_in, const int* in_sizes, int n_in,
                              void* d_out, int out_size, void* d_ws, size_t ws_size,
                              hipStream_t stream)
{
    const float* x     = (const float*)d_in[0];
    const int*   ei    = (const int*)d_in[1];
    const float* ew    = (const float*)d_in[2];
    const float* Wrel  = (const float*)d_in[3];
    const float* brel  = (const float*)d_in[4];
    const float* Wroot = (const float*)d_in[5];
    float* out = (float*)d_out;

    int N = in_sizes[0] / D;
    int E = in_sizes[2];
    const int* src = ei;
    const int* dst = ei + E;

    // Workspace layout
    float* agg     = (float*)d_ws;                        // N*D floats
    float* h2      = agg + (size_t)N * D;                 // N*D floats
    int*   ssrc    = (int*)(h2 + (size_t)N * D);          // E ints
    float* sw      = (float*)(ssrc + E);                  // E floats
    int*   row_ptr = (int*)(sw + E);                      // N+1 ints
    int*   cursor  = row_ptr + (N + 1);                   // N ints
    int*   counts  = cursor + N;                          // N ints

    dim3 blk256(256);
    dim3 grdE((E + 255) / 256);
    dim3 grdGather((N * 64 + 255) / 256);
    dim3 grdGemm((N + 63) / 64);

    // --- CSR build (once, reused by all 3 layers) ---
    hipMemsetAsync(counts, 0, (size_t)N * sizeof(int), stream);
    hist_kernel<<<grdE, blk256, 0, stream>>>(dst, counts, E);
    scan_kernel<<<1, 1024, 0, stream>>>(counts, row_ptr, cursor, N, E);
    scatter_csr_kernel<<<grdE, blk256, 0, stream>>>(src, dst, ew, cursor, ssrc, sw, E);

    // --- Layer 0: x -> out (relu) ---
    gather_csr_kernel<<<grdGather, blk256, 0, stream>>>(x, ssrc, sw, row_ptr, agg, N);
    gemm_fused<<<grdGemm, blk256, 0, stream>>>(agg, x, Wrel, brel, Wroot, out, N, 1);

    // --- Layer 1: out -> h2 (relu) ---
    gather_csr_kernel<<<grdGather, blk256, 0, stream>>>(out, ssrc, sw, row_ptr, agg, N);
    gemm_fused<<<grdGemm, blk256, 0, stream>>>(agg, out, Wrel + 128 * 128, brel + 128,
                                               Wroot + 128 * 128, h2, N, 1);

    // --- Layer 2: h2 -> out (no relu) ---
    gather_csr_kernel<<<grdGather, blk256, 0, stream>>>(h2, ssrc, sw, row_ptr, agg, N);
    gemm_fused<<<grdGemm, blk256, 0, stream>>>(agg, h2, Wrel + 2 * 128 * 128, brel + 2 * 128,
                                               Wroot + 2 * 128 * 128, out, N, 0);
}

// Round 3
// 455.893 us; speedup vs baseline: 9.2657x; 1.2088x over previous
//
#include <hip/hip_runtime.h>

#define D 128

// ---------------------------------------------------------------------------
// CSR build step 1: histogram of dst
// ---------------------------------------------------------------------------
__global__ __launch_bounds__(256) void hist_kernel(
    const int* __restrict__ dst, int* __restrict__ counts, int E)
{
    int e = blockIdx.x * 256 + threadIdx.x;
    if (e < E) atomicAdd(&counts[dst[e]], 1);
}

// ---------------------------------------------------------------------------
// CSR build step 2a: per-block (256-chunk) sums of counts
// ---------------------------------------------------------------------------
__global__ __launch_bounds__(256) void blocksum_kernel(
    const int* __restrict__ counts, int* __restrict__ bsums, int N)
{
    __shared__ int red[256];
    int t = threadIdx.x;
    int i = blockIdx.x * 256 + t;
    red[t] = (i < N) ? counts[i] : 0;
    __syncthreads();
    #pragma unroll
    for (int off = 128; off > 0; off >>= 1) {
        if (t < off) red[t] += red[t + off];
        __syncthreads();
    }
    if (t == 0) bsums[blockIdx.x] = red[0];
}

// ---------------------------------------------------------------------------
// CSR build step 2b: exclusive scan of block sums (nb <= 256), one block
// ---------------------------------------------------------------------------
__global__ __launch_bounds__(256) void scansums_kernel(
    int* __restrict__ bsums, int nb)
{
    __shared__ int s[256];
    int t = threadIdx.x;
    int v = (t < nb) ? bsums[t] : 0;
    s[t] = v;
    __syncthreads();
    #pragma unroll
    for (int off = 1; off < 256; off <<= 1) {
        int tmp = (t >= off) ? s[t - off] : 0;
        __syncthreads();
        s[t] += tmp;
        __syncthreads();
    }
    if (t < nb) bsums[t] = s[t] - v;   // exclusive
}

// ---------------------------------------------------------------------------
// CSR build step 2c: per-chunk exclusive scan + block offset -> row_ptr/cursor
// ---------------------------------------------------------------------------
__global__ __launch_bounds__(256) void emit_kernel(
    const int* __restrict__ counts, const int* __restrict__ bsums,
    int* __restrict__ row_ptr, int* __restrict__ cursor, int N, int E)
{
    __shared__ int s[256];
    int t = threadIdx.x;
    int i = blockIdx.x * 256 + t;
    int v = (i < N) ? counts[i] : 0;
    s[t] = v;
    __syncthreads();
    #pragma unroll
    for (int off = 1; off < 256; off <<= 1) {
        int tmp = (t >= off) ? s[t - off] : 0;
        __syncthreads();
        s[t] += tmp;
        __syncthreads();
    }
    int excl = s[t] - v + bsums[blockIdx.x];
    if (i < N) {
        row_ptr[i] = excl;
        cursor[i]  = excl;
    }
    if (blockIdx.x == 0 && t == 0) row_ptr[N] = E;
}

// ---------------------------------------------------------------------------
// CSR build step 3: scatter (src, w) into dst-sorted order
// ---------------------------------------------------------------------------
__global__ __launch_bounds__(256) void scatter_csr_kernel(
    const int* __restrict__ src, const int* __restrict__ dst,
    const float* __restrict__ ew, int* __restrict__ cursor,
    int* __restrict__ ssrc, float* __restrict__ sw, int E)
{
    int e = blockIdx.x * 256 + threadIdx.x;
    if (e >= E) return;
    int d = dst[e];
    int pos = atomicAdd(&cursor[d], 1);
    ssrc[pos] = src[e];
    sw[pos]   = ew[e];
}

// ---------------------------------------------------------------------------
// Aggregation: one 64-lane wave per node. Lane holds float2 of the feature
// row. Edge (src,w) pairs loaded coalesced 64-at-a-time, broadcast via shfl.
// ---------------------------------------------------------------------------
__global__ __launch_bounds__(256) void gather_csr_kernel(
    const float* __restrict__ h, const int* __restrict__ ssrc,
    const float* __restrict__ sw, const int* __restrict__ row_ptr,
    float* __restrict__ agg, int N)
{
    int wave = (blockIdx.x * 256 + threadIdx.x) >> 6;
    int lane = threadIdx.x & 63;
    if (wave >= N) return;

    int beg = row_ptr[wave];
    int cnt = row_ptr[wave + 1] - beg;

    float2 acc0 = make_float2(0.f, 0.f);
    float2 acc1 = make_float2(0.f, 0.f);

    for (int base = 0; base < cnt; base += 64) {
        int k = base + lane;
        int sv = 0; float wv = 0.f;
        if (k < cnt) { sv = ssrc[beg + k]; wv = sw[beg + k]; }
        int m = min(64, cnt - base);
        int j = 0;
        for (; j + 1 < m; j += 2) {
            int   s0 = __shfl(sv, j);
            float w0 = __shfl(wv, j);
            int   s1 = __shfl(sv, j + 1);
            float w1 = __shfl(wv, j + 1);
            float2 v0 = *(const float2*)(h + (size_t)s0 * D + lane * 2);
            float2 v1 = *(const float2*)(h + (size_t)s1 * D + lane * 2);
            acc0.x = fmaf(w0, v0.x, acc0.x);
            acc0.y = fmaf(w0, v0.y, acc0.y);
            acc1.x = fmaf(w1, v1.x, acc1.x);
            acc1.y = fmaf(w1, v1.y, acc1.y);
        }
        if (j < m) {
            int   s0 = __shfl(sv, j);
            float w0 = __shfl(wv, j);
            float2 v0 = *(const float2*)(h + (size_t)s0 * D + lane * 2);
            acc0.x = fmaf(w0, v0.x, acc0.x);
            acc0.y = fmaf(w0, v0.y, acc0.y);
        }
    }
    acc0.x += acc1.x;
    acc0.y += acc1.y;
    *(float2*)(agg + (size_t)wave * D + lane * 2) = acc0;
}

// ---------------------------------------------------------------------------
// Fused GEMM: out = agg @ Wrel + b + h @ Wroot, optional relu.
// Block: 256 threads, 64 rows x 128 cols. Thread: 8 rows x 4 cols.
// ---------------------------------------------------------------------------
#define FMA4(ACC, AV, W0, W1, W2, W3)                    \
    do {                                                 \
        ACC.x = fmaf(AV.x, W0.x, ACC.x);                 \
        ACC.y = fmaf(AV.x, W0.y, ACC.y);                 \
        ACC.z = fmaf(AV.x, W0.z, ACC.z);                 \
        ACC.w = fmaf(AV.x, W0.w, ACC.w);                 \
        ACC.x = fmaf(AV.y, W1.x, ACC.x);                 \
        ACC.y = fmaf(AV.y, W1.y, ACC.y);                 \
        ACC.z = fmaf(AV.y, W1.z, ACC.z);                 \
        ACC.w = fmaf(AV.y, W1.w, ACC.w);                 \
        ACC.x = fmaf(AV.z, W2.x, ACC.x);                 \
        ACC.y = fmaf(AV.z, W2.y, ACC.y);                 \
        ACC.z = fmaf(AV.z, W2.z, ACC.z);                 \
        ACC.w = fmaf(AV.z, W2.w, ACC.w);                 \
        ACC.x = fmaf(AV.w, W3.x, ACC.x);                 \
        ACC.y = fmaf(AV.w, W3.y, ACC.y);                 \
        ACC.z = fmaf(AV.w, W3.z, ACC.z);                 \
        ACC.w = fmaf(AV.w, W3.w, ACC.w);                 \
    } while (0)

__global__ __launch_bounds__(256, 2) void gemm_fused(
    const float* __restrict__ agg, const float* __restrict__ h,
    const float* __restrict__ Wrel, const float* __restrict__ bias,
    const float* __restrict__ Wroot, float* __restrict__ out,
    int N, int relu)
{
    __shared__ float a_s[64 * 256];
    int tid = threadIdx.x;
    int row0 = blockIdx.x * 64;

    #pragma unroll
    for (int j = 0; j < 16; ++j) {
        int f = j * 256 + tid;
        int r = f >> 6;
        int q = f & 63;
        int gr = row0 + r;
        float4 v = make_float4(0.f, 0.f, 0.f, 0.f);
        if (gr < N) {
            const float* p = (q < 32) ? (agg + (size_t)gr * D + q * 4)
                                      : (h + (size_t)gr * D + (q - 32) * 4);
            v = *(const float4*)p;
        }
        *(float4*)&a_s[r * 256 + q * 4] = v;
    }
    __syncthreads();

    int colg = tid & 31;
    int rowg = tid >> 5;
    int c0 = colg * 4;

    float4 acc[8];
    #pragma unroll
    for (int i = 0; i < 8; ++i) acc[i] = make_float4(0.f, 0.f, 0.f, 0.f);

    #pragma unroll 2
    for (int k = 0; k < 128; k += 4) {
        float4 w0 = *(const float4*)(Wrel + (size_t)(k + 0) * D + c0);
        float4 w1 = *(const float4*)(Wrel + (size_t)(k + 1) * D + c0);
        float4 w2 = *(const float4*)(Wrel + (size_t)(k + 2) * D + c0);
        float4 w3 = *(const float4*)(Wrel + (size_t)(k + 3) * D + c0);
        #pragma unroll
        for (int i = 0; i < 8; ++i) {
            float4 av = *(const float4*)&a_s[(rowg * 8 + i) * 256 + k];
            FMA4(acc[i], av, w0, w1, w2, w3);
        }
    }
    #pragma unroll 2
    for (int k = 0; k < 128; k += 4) {
        float4 w0 = *(const float4*)(Wroot + (size_t)(k + 0) * D + c0);
        float4 w1 = *(const float4*)(Wroot + (size_t)(k + 1) * D + c0);
        float4 w2 = *(const float4*)(Wroot + (size_t)(k + 2) * D + c0);
        float4 w3 = *(const float4*)(Wroot + (size_t)(k + 3) * D + c0);
        #pragma unroll
        for (int i = 0; i < 8; ++i) {
            float4 av = *(const float4*)&a_s[(rowg * 8 + i) * 256 + 128 + k];
            FMA4(acc[i], av, w0, w1, w2, w3);
        }
    }

    float4 bv = *(const float4*)(bias + c0);
    #pragma unroll
    for (int i = 0; i < 8; ++i) {
        int gr = row0 + rowg * 8 + i;
        if (gr < N) {
            float4 o = acc[i];
            o.x += bv.x; o.y += bv.y; o.z += bv.z; o.w += bv.w;
            if (relu) {
                o.x = fmaxf(o.x, 0.f); o.y = fmaxf(o.y, 0.f);
                o.z = fmaxf(o.z, 0.f); o.w = fmaxf(o.w, 0.f);
            }
            *(float4*)(out + (size_t)gr * D + c0) = o;
        }
    }
}

// ---------------------------------------------------------------------------
extern "C" void kernel_launch(void* const* d_in, const int* in_sizes, int n_in,
                              void* d_out, int out_size, void* d_ws, size_t ws_size,
                              hipStream_t stream)
{
    const float* x     = (const float*)d_in[0];
    const int*   ei    = (const int*)d_in[1];
    const float* ew    = (const float*)d_in[2];
    const float* Wrel  = (const float*)d_in[3];
    const float* brel  = (const float*)d_in[4];
    const float* Wroot = (const float*)d_in[5];
    float* out = (float*)d_out;

    int N = in_sizes[0] / D;
    int E = in_sizes[2];
    const int* src = ei;
    const int* dst = ei + E;

    int nb = (N + 255) / 256;   // 196 for N=50000 (must be <= 256)

    // Workspace layout
    float* agg     = (float*)d_ws;                        // N*D floats
    float* h2      = agg + (size_t)N * D;                 // N*D floats
    int*   ssrc    = (int*)(h2 + (size_t)N * D);          // E ints
    float* sw      = (float*)(ssrc + E);                  // E floats
    int*   row_ptr = (int*)(sw + E);                      // N+1 ints
    int*   cursor  = row_ptr + (N + 1);                   // N ints
    int*   counts  = cursor + N;                          // N ints
    int*   bsums   = counts + N;                          // nb ints

    dim3 blk256(256);
    dim3 grdE((E + 255) / 256);
    dim3 grdN(nb);
    dim3 grdGather((N * 64 + 255) / 256);
    dim3 grdGemm((N + 63) / 64);

    // --- CSR build (once, reused by all 3 layers) ---
    hipMemsetAsync(counts, 0, (size_t)N * sizeof(int), stream);
    hist_kernel<<<grdE, blk256, 0, stream>>>(dst, counts, E);
    blocksum_kernel<<<grdN, blk256, 0, stream>>>(counts, bsums, N);
    scansums_kernel<<<1, blk256, 0, stream>>>(bsums, nb);
    emit_kernel<<<grdN, blk256, 0, stream>>>(counts, bsums, row_ptr, cursor, N, E);
    scatter_csr_kernel<<<grdE, blk256, 0, stream>>>(src, dst, ew, cursor, ssrc, sw, E);

    // --- Layer 0: x -> out (relu) ---
    gather_csr_kernel<<<grdGather, blk256, 0, stream>>>(x, ssrc, sw, row_ptr, agg, N);
    gemm_fused<<<grdGemm, blk256, 0, stream>>>(agg, x, Wrel, brel, Wroot, out, N, 1);

    // --- Layer 1: out -> h2 (relu) ---
    gather_csr_kernel<<<grdGather, blk256, 0, stream>>>(out, ssrc, sw, row_ptr, agg, N);
    gemm_fused<<<grdGemm, blk256, 0, stream>>>(agg, out, Wrel + 128 * 128, brel + 128,
                                               Wroot + 128 * 128, h2, N, 1);

    // --- Layer 2: h2 -> out (no relu) ---
    gather_csr_kernel<<<grdGather, blk256, 0, stream>>>(h2, ssrc, sw, row_ptr, agg, N);
    gemm_fused<<<grdGemm, blk256, 0, stream>>>(agg, h2, Wrel + 2 * 128 * 128, brel + 2 * 128,
                                               Wroot + 2 * 128 * 128, out, N, 0);
}

// Round 4
// 410.412 us; speedup vs baseline: 10.2925x; 1.1108x over previous
//
#include <hip/hip_runtime.h>

#define D 128

typedef __attribute__((ext_vector_type(8))) short bf16x8;
typedef __attribute__((ext_vector_type(4))) float f32x4;

__device__ __forceinline__ float uif(unsigned u) { return __uint_as_float(u); }
__device__ __forceinline__ unsigned short f2bf(float f) {
    unsigned u = __float_as_uint(f);
    u += 0x7fffu + ((u >> 16) & 1u);     // RNE to bf16
    return (unsigned short)(u >> 16);
}
__device__ __forceinline__ float bf2f(unsigned short h) {
    return __uint_as_float(((unsigned)h) << 16);
}

// ---------------------------------------------------------------------------
// CSR build: histogram -> scan (3-kernel) -> position scatter
// ---------------------------------------------------------------------------
__global__ __launch_bounds__(256) void hist_kernel(
    const int* __restrict__ dst, int* __restrict__ counts, int E)
{
    int e = blockIdx.x * 256 + threadIdx.x;
    if (e < E) atomicAdd(&counts[dst[e]], 1);
}

__global__ __launch_bounds__(256) void blocksum_kernel(
    const int* __restrict__ counts, int* __restrict__ bsums, int N)
{
    __shared__ int red[256];
    int t = threadIdx.x;
    int i = blockIdx.x * 256 + t;
    red[t] = (i < N) ? counts[i] : 0;
    __syncthreads();
    #pragma unroll
    for (int off = 128; off > 0; off >>= 1) {
        if (t < off) red[t] += red[t + off];
        __syncthreads();
    }
    if (t == 0) bsums[blockIdx.x] = red[0];
}

__global__ __launch_bounds__(256) void scansums_kernel(
    int* __restrict__ bsums, int nb)
{
    __shared__ int s[256];
    int t = threadIdx.x;
    int v = (t < nb) ? bsums[t] : 0;
    s[t] = v;
    __syncthreads();
    #pragma unroll
    for (int off = 1; off < 256; off <<= 1) {
        int tmp = (t >= off) ? s[t - off] : 0;
        __syncthreads();
        s[t] += tmp;
        __syncthreads();
    }
    if (t < nb) bsums[t] = s[t] - v;
}

__global__ __launch_bounds__(256) void emit_kernel(
    const int* __restrict__ counts, const int* __restrict__ bsums,
    int* __restrict__ row_ptr, int* __restrict__ cursor, int N, int E)
{
    __shared__ int s[256];
    int t = threadIdx.x;
    int i = blockIdx.x * 256 + t;
    int v = (i < N) ? counts[i] : 0;
    s[t] = v;
    __syncthreads();
    #pragma unroll
    for (int off = 1; off < 256; off <<= 1) {
        int tmp = (t >= off) ? s[t - off] : 0;
        __syncthreads();
        s[t] += tmp;
        __syncthreads();
    }
    int excl = s[t] - v + bsums[blockIdx.x];
    if (i < N) { row_ptr[i] = excl; cursor[i] = excl; }
    if (blockIdx.x == 0 && t == 0) row_ptr[N] = E;
}

__global__ __launch_bounds__(256) void scatter_csr_kernel(
    const int* __restrict__ src, const int* __restrict__ dst,
    const float* __restrict__ ew, int* __restrict__ cursor,
    int* __restrict__ ssrc, float* __restrict__ sw, int E)
{
    int e = blockIdx.x * 256 + threadIdx.x;
    if (e >= E) return;
    int d = dst[e];
    int pos = atomicAdd(&cursor[d], 1);
    ssrc[pos] = src[e];
    sw[pos]   = ew[e];
}

// ---------------------------------------------------------------------------
// Converts: x -> h-region hi/lo of A; W -> transposed hi/lo bf16 (all layers)
// A layout: [Npad][256] bf16 per plane; cols 0-127 = agg, 128-255 = h.
// WT layout: [L][128 cols][256 k] bf16; k 0-127 = Wrel rows, 128-255 = Wroot.
// ---------------------------------------------------------------------------
__global__ __launch_bounds__(256) void convert_x_kernel(
    const float* __restrict__ x, short* __restrict__ Ahi,
    short* __restrict__ Alo, int N)
{
    int t = blockIdx.x * 256 + threadIdx.x;   // over N*64 (pairs of cols)
    if (t >= N * 64) return;
    int row = t >> 6;
    int c2  = (t & 63) * 2;
    float2 v = *(const float2*)(x + (size_t)row * D + c2);
    unsigned short hx = f2bf(v.x), hy = f2bf(v.y);
    unsigned short lx = f2bf(v.x - bf2f(hx)), ly = f2bf(v.y - bf2f(hy));
    *(unsigned*)(Ahi + (size_t)row * 256 + 128 + c2) = ((unsigned)hy << 16) | hx;
    *(unsigned*)(Alo + (size_t)row * 256 + 128 + c2) = ((unsigned)ly << 16) | lx;
}

__global__ __launch_bounds__(256) void convert_w_kernel(
    const float* __restrict__ Wrel, const float* __restrict__ Wroot,
    short* __restrict__ WhiT, short* __restrict__ WloT, int total)
{
    int t = blockIdx.x * 256 + threadIdx.x;   // over L*32768
    if (t >= total) return;
    int l = t >> 15;
    int rem = t & 32767;
    int k = rem >> 7;
    int c = rem & 127;
    float f = (k < 128) ? Wrel[(size_t)l * 16384 + k * D + c]
                        : Wroot[(size_t)l * 16384 + (k - 128) * D + c];
    unsigned short h = f2bf(f);
    WhiT[(size_t)l * 32768 + c * 256 + k] = (short)h;
    WloT[(size_t)l * 32768 + c * 256 + k] = (short)f2bf(f - bf2f(h));
}

// ---------------------------------------------------------------------------
// Aggregation: one wave per node; reads h-region (hi+lo reconstruct),
// writes agg-region as hi/lo.
// ---------------------------------------------------------------------------
__global__ __launch_bounds__(256) void gather_bf16(
    short* __restrict__ Ahi, short* __restrict__ Alo,
    const int* __restrict__ ssrc, const float* __restrict__ sw,
    const int* __restrict__ row_ptr, int N)
{
    int wave = (blockIdx.x * 256 + threadIdx.x) >> 6;
    int lane = threadIdx.x & 63;
    if (wave >= N) return;
    int beg = row_ptr[wave];
    int cnt = row_ptr[wave + 1] - beg;
    int hoff = 128 + lane * 2;

    float a0x = 0.f, a0y = 0.f, a1x = 0.f, a1y = 0.f;

    for (int base = 0; base < cnt; base += 64) {
        int k = base + lane;
        int sv = 0; float wv = 0.f;
        if (k < cnt) { sv = ssrc[beg + k]; wv = sw[beg + k]; }
        int m = min(64, cnt - base);
        int j = 0;
        for (; j + 1 < m; j += 2) {
            int   s0 = __shfl(sv, j);     float w0 = __shfl(wv, j);
            int   s1 = __shfl(sv, j + 1); float w1 = __shfl(wv, j + 1);
            unsigned h0 = *(const unsigned*)(Ahi + (size_t)s0 * 256 + hoff);
            unsigned l0 = *(const unsigned*)(Alo + (size_t)s0 * 256 + hoff);
            unsigned h1 = *(const unsigned*)(Ahi + (size_t)s1 * 256 + hoff);
            unsigned l1 = *(const unsigned*)(Alo + (size_t)s1 * 256 + hoff);
            a0x = fmaf(w0, uif(h0 << 16) + uif(l0 << 16), a0x);
            a0y = fmaf(w0, uif(h0 & 0xffff0000u) + uif(l0 & 0xffff0000u), a0y);
            a1x = fmaf(w1, uif(h1 << 16) + uif(l1 << 16), a1x);
            a1y = fmaf(w1, uif(h1 & 0xffff0000u) + uif(l1 & 0xffff0000u), a1y);
        }
        if (j < m) {
            int s0 = __shfl(sv, j); float w0 = __shfl(wv, j);
            unsigned h0 = *(const unsigned*)(Ahi + (size_t)s0 * 256 + hoff);
            unsigned l0 = *(const unsigned*)(Alo + (size_t)s0 * 256 + hoff);
            a0x = fmaf(w0, uif(h0 << 16) + uif(l0 << 16), a0x);
            a0y = fmaf(w0, uif(h0 & 0xffff0000u) + uif(l0 & 0xffff0000u), a0y);
        }
    }
    float ax = a0x + a1x, ay = a0y + a1y;
    unsigned short hx = f2bf(ax), hy = f2bf(ay);
    unsigned short lx = f2bf(ax - bf2f(hx)), ly = f2bf(ay - bf2f(hy));
    *(unsigned*)(Ahi + (size_t)wave * 256 + lane * 2) = ((unsigned)hy << 16) | hx;
    *(unsigned*)(Alo + (size_t)wave * 256 + lane * 2) = ((unsigned)ly << 16) | lx;
}

// ---------------------------------------------------------------------------
// MFMA GEMM: acc = Ahi@Whi + Alo@Whi + Ahi@Wlo over K=256 ([agg|h] concat).
// Block: 64 rows x 128 cols, 4 waves (2x2), wave tile 32x64, 16x16x32 frags.
// W^T staged in 64KB LDS with XOR swizzle (unit ^= col&7); A direct global.
// Epilogue: layer<L-1 -> write h-region hi/lo (relu); last -> fp32 d_out.
// ---------------------------------------------------------------------------
#define STAGE_W(WSRC)                                                           \
    _Pragma("unroll")                                                           \
    for (int r = 0; r < 16; ++r) {                                              \
        int u = r * 256 + tid;                                                  \
        bf16x8 v = *(const bf16x8*)((WSRC) + (size_t)u * 8);                    \
        int scol = u >> 5, sku = u & 31;                                        \
        *(bf16x8*)((char*)bsh + scol * 512 + ((sku ^ (scol & 7)) << 4)) = v;    \
    }

#define MFMA_PASS(APTR)                                                         \
    _Pragma("unroll")                                                           \
    for (int ks = 0; ks < 8; ++ks) {                                            \
        bf16x8 a0 = *(const bf16x8*)((APTR) + aoff0 + ks * 32 + l4 * 8);        \
        bf16x8 a1 = *(const bf16x8*)((APTR) + aoff1 + ks * 32 + l4 * 8);        \
        _Pragma("unroll")                                                       \
        for (int n = 0; n < 4; ++n) {                                           \
            int col = wc * 64 + n * 16 + l15;                                   \
            int ku = ks * 4 + l4;                                               \
            bf16x8 b = *(const bf16x8*)((const char*)bsh + col * 512            \
                                        + ((ku ^ (col & 7)) << 4));             \
            acc0[n] = __builtin_amdgcn_mfma_f32_16x16x32_bf16(a0, b, acc0[n], 0, 0, 0); \
            acc1[n] = __builtin_amdgcn_mfma_f32_16x16x32_bf16(a1, b, acc1[n], 0, 0, 0); \
        }                                                                       \
    }

__global__ __launch_bounds__(256, 2) void gemm_mfma(
    short* __restrict__ Ahi, short* __restrict__ Alo,
    const short* __restrict__ WhiT, const short* __restrict__ WloT,
    const float* __restrict__ bias, float* __restrict__ outf,
    int N, int relu, int writef)
{
    __shared__ short bsh[32768];   // 64 KB: [128 cols][256 k] bf16, swizzled
    int tid = threadIdx.x;
    int lane = tid & 63;
    int wid = tid >> 6;
    int wr = wid >> 1, wc = wid & 1;
    int l15 = lane & 15, l4 = lane >> 4;
    int row0 = blockIdx.x * 64;

    size_t aoff0 = (size_t)(row0 + wr * 32 + l15) * 256;
    size_t aoff1 = aoff0 + 16 * 256;

    f32x4 acc0[4], acc1[4];
    #pragma unroll
    for (int n = 0; n < 4; ++n) {
        acc0[n] = (f32x4){0.f, 0.f, 0.f, 0.f};
        acc1[n] = (f32x4){0.f, 0.f, 0.f, 0.f};
    }

    STAGE_W(WhiT);
    __syncthreads();
    MFMA_PASS(Ahi);        // A_hi @ W_hi
    MFMA_PASS(Alo);        // A_lo @ W_hi
    __syncthreads();
    STAGE_W(WloT);
    __syncthreads();
    MFMA_PASS(Ahi);        // A_hi @ W_lo
    __syncthreads();       // all reads of A done before h-region overwrite

    #pragma unroll
    for (int n = 0; n < 4; ++n) {
        int col = wc * 64 + n * 16 + l15;
        float bv = bias[col];
        #pragma unroll
        for (int m = 0; m < 2; ++m) {
            f32x4 a = (m == 0) ? acc0[n] : acc1[n];
            #pragma unroll
            for (int r = 0; r < 4; ++r) {
                int row = row0 + wr * 32 + m * 16 + l4 * 4 + r;
                if (row < N) {
                    float v = a[r] + bv;
                    if (relu) v = fmaxf(v, 0.f);
                    if (writef) {
                        outf[(size_t)row * D + col] = v;
                    } else {
                        unsigned short h = f2bf(v);
                        Ahi[(size_t)row * 256 + 128 + col] = (short)h;
                        Alo[(size_t)row * 256 + 128 + col] = (short)f2bf(v - bf2f(h));
                    }
                }
            }
        }
    }
}

// ---------------------------------------------------------------------------
extern "C" void kernel_launch(void* const* d_in, const int* in_sizes, int n_in,
                              void* d_out, int out_size, void* d_ws, size_t ws_size,
                              hipStream_t stream)
{
    const float* x     = (const float*)d_in[0];
    const int*   ei    = (const int*)d_in[1];
    const float* ew    = (const float*)d_in[2];
    const float* Wrel  = (const float*)d_in[3];
    const float* brel  = (const float*)d_in[4];
    const float* Wroot = (const float*)d_in[5];
    float* out = (float*)d_out;

    int N = in_sizes[0] / D;
    int E = in_sizes[2];
    int L = in_sizes[3] / (D * D);
    int Npad = ((N + 63) / 64) * 64;
    const int* src = ei;
    const int* dst = ei + E;
    int nb = (N + 255) / 256;

    // Workspace layout
    short* Ahi  = (short*)d_ws;                        // Npad*256
    short* Alo  = Ahi + (size_t)Npad * 256;            // Npad*256
    short* WhiT = Alo + (size_t)Npad * 256;            // L*32768
    short* WloT = WhiT + (size_t)L * 32768;            // L*32768
    int*   ssrc    = (int*)(WloT + (size_t)L * 32768); // E
    float* sw      = (float*)(ssrc + E);               // E
    int*   row_ptr = (int*)(sw + E);                   // N+1
    int*   cursor  = row_ptr + (N + 1);                // N
    int*   counts  = cursor + N;                       // N
    int*   bsums   = counts + N;                       // nb

    dim3 blk256(256);
    dim3 grdE((E + 255) / 256);
    dim3 grdN(nb);
    dim3 grdGather((N * 64 + 255) / 256);
    dim3 grdGemm(Npad / 64);
    dim3 grdCX((N * 64 + 255) / 256);
    dim3 grdCW((L * 32768 + 255) / 256);

    // --- CSR build (once) ---
    hipMemsetAsync(counts, 0, (size_t)N * sizeof(int), stream);
    hist_kernel<<<grdE, blk256, 0, stream>>>(dst, counts, E);
    blocksum_kernel<<<grdN, blk256, 0, stream>>>(counts, bsums, N);
    scansums_kernel<<<1, blk256, 0, stream>>>(bsums, nb);
    emit_kernel<<<grdN, blk256, 0, stream>>>(counts, bsums, row_ptr, cursor, N, E);
    scatter_csr_kernel<<<grdE, blk256, 0, stream>>>(src, dst, ew, cursor, ssrc, sw, E);

    // --- hi/lo conversions (once) ---
    convert_w_kernel<<<grdCW, blk256, 0, stream>>>(Wrel, Wroot, WhiT, WloT, L * 32768);
    convert_x_kernel<<<grdCX, blk256, 0, stream>>>(x, Ahi, Alo, N);

    // --- layers ---
    for (int l = 0; l < L; ++l) {
        gather_bf16<<<grdGather, blk256, 0, stream>>>(Ahi, Alo, ssrc, sw, row_ptr, N);
        gemm_mfma<<<grdGemm, blk256, 0, stream>>>(
            Ahi, Alo, WhiT + (size_t)l * 32768, WloT + (size_t)l * 32768,
            brel + (size_t)l * D, out, N, (l < L - 1) ? 1 : 0, (l == L - 1) ? 1 : 0);
    }
}

// Round 5
// 332.193 us; speedup vs baseline: 12.7159x; 1.2355x over previous
//
#include <hip/hip_runtime.h>

#define D 128

typedef __attribute__((ext_vector_type(8))) short bf16x8;
typedef __attribute__((ext_vector_type(4))) float f32x4;

__device__ __forceinline__ float uif(unsigned u) { return __uint_as_float(u); }
__device__ __forceinline__ unsigned short f2bf(float f) {
    unsigned u = __float_as_uint(f);
    u += 0x7fffu + ((u >> 16) & 1u);     // RNE to bf16
    return (unsigned short)(u >> 16);
}
__device__ __forceinline__ float bf2f(unsigned short h) {
    return __uint_as_float(((unsigned)h) << 16);
}

// ---------------------------------------------------------------------------
// CSR build: histogram -> scan (3-kernel) -> position scatter (packed 8B)
// ---------------------------------------------------------------------------
__global__ __launch_bounds__(256) void hist_kernel(
    const int* __restrict__ dst, int* __restrict__ counts, int E)
{
    int e = blockIdx.x * 256 + threadIdx.x;
    if (e < E) atomicAdd(&counts[dst[e]], 1);
}

__global__ __launch_bounds__(256) void blocksum_kernel(
    const int* __restrict__ counts, int* __restrict__ bsums, int N)
{
    __shared__ int red[256];
    int t = threadIdx.x;
    int i = blockIdx.x * 256 + t;
    red[t] = (i < N) ? counts[i] : 0;
    __syncthreads();
    #pragma unroll
    for (int off = 128; off > 0; off >>= 1) {
        if (t < off) red[t] += red[t + off];
        __syncthreads();
    }
    if (t == 0) bsums[blockIdx.x] = red[0];
}

__global__ __launch_bounds__(256) void scansums_kernel(
    int* __restrict__ bsums, int nb)
{
    __shared__ int s[256];
    int t = threadIdx.x;
    int v = (t < nb) ? bsums[t] : 0;
    s[t] = v;
    __syncthreads();
    #pragma unroll
    for (int off = 1; off < 256; off <<= 1) {
        int tmp = (t >= off) ? s[t - off] : 0;
        __syncthreads();
        s[t] += tmp;
        __syncthreads();
    }
    if (t < nb) bsums[t] = s[t] - v;
}

__global__ __launch_bounds__(256) void emit_kernel(
    const int* __restrict__ counts, const int* __restrict__ bsums,
    int* __restrict__ row_ptr, int* __restrict__ cursor, int N, int E)
{
    __shared__ int s[256];
    int t = threadIdx.x;
    int i = blockIdx.x * 256 + t;
    int v = (i < N) ? counts[i] : 0;
    s[t] = v;
    __syncthreads();
    #pragma unroll
    for (int off = 1; off < 256; off <<= 1) {
        int tmp = (t >= off) ? s[t - off] : 0;
        __syncthreads();
        s[t] += tmp;
        __syncthreads();
    }
    int excl = s[t] - v + bsums[blockIdx.x];
    if (i < N) { row_ptr[i] = excl; cursor[i] = excl; }
    if (blockIdx.x == 0 && t == 0) row_ptr[N] = E;
}

__global__ __launch_bounds__(256) void scatter_csr_kernel(
    const int* __restrict__ src, const int* __restrict__ dst,
    const float* __restrict__ ew, int* __restrict__ cursor,
    int2* __restrict__ edata, int E)
{
    int e = blockIdx.x * 256 + threadIdx.x;
    if (e >= E) return;
    int d = dst[e];
    int pos = atomicAdd(&cursor[d], 1);
    edata[pos] = make_int2(src[e], __float_as_int(ew[e]));
}

// ---------------------------------------------------------------------------
// Converts. A layout per plane: [Npad][256] bf16; cols 0-127 = agg (hi+lo),
// cols 128-255 = h (hi only; Alo h-region is zeroed once per call).
// WT layout: [L][128 cols][256 k] bf16; k 0-127 = Wrel rows, 128-255 = Wroot.
// ---------------------------------------------------------------------------
__global__ __launch_bounds__(256) void convert_x_kernel(
    const float* __restrict__ x, short* __restrict__ Ahi, int N)
{
    int t = blockIdx.x * 256 + threadIdx.x;   // over N*64 (pairs of cols)
    if (t >= N * 64) return;
    int row = t >> 6;
    int c2  = (t & 63) * 2;
    float2 v = *(const float2*)(x + (size_t)row * D + c2);
    *(unsigned*)(Ahi + (size_t)row * 256 + 128 + c2) =
        ((unsigned)f2bf(v.y) << 16) | f2bf(v.x);
}

__global__ __launch_bounds__(256) void convert_w_kernel(
    const float* __restrict__ Wrel, const float* __restrict__ Wroot,
    short* __restrict__ WhiT, short* __restrict__ WloT, int total)
{
    int t = blockIdx.x * 256 + threadIdx.x;   // over L*32768
    if (t >= total) return;
    int l = t >> 15;
    int rem = t & 32767;
    int k = rem >> 7;
    int c = rem & 127;
    float f = (k < 128) ? Wrel[(size_t)l * 16384 + k * D + c]
                        : Wroot[(size_t)l * 16384 + (k - 128) * D + c];
    unsigned short h = f2bf(f);
    WhiT[(size_t)l * 32768 + c * 256 + k] = (short)h;
    WloT[(size_t)l * 32768 + c * 256 + k] = (short)f2bf(f - bf2f(h));
}

// ---------------------------------------------------------------------------
// Aggregation: one wave per node; reads h-region (bf16 hi only),
// writes agg-region as hi/lo. Edge (src,w) packed 8B, unroll x4.
// ---------------------------------------------------------------------------
__global__ __launch_bounds__(256) void gather_bf16(
    short* __restrict__ Ahi, short* __restrict__ Alo,
    const int2* __restrict__ edata, const int* __restrict__ row_ptr, int N)
{
    int wave = (blockIdx.x * 256 + threadIdx.x) >> 6;
    int lane = threadIdx.x & 63;
    if (wave >= N) return;
    int beg = row_ptr[wave];
    int cnt = row_ptr[wave + 1] - beg;
    int hoff = 128 + lane * 2;

    float ax0 = 0.f, ay0 = 0.f, ax1 = 0.f, ay1 = 0.f;
    float ax2 = 0.f, ay2 = 0.f, ax3 = 0.f, ay3 = 0.f;

    for (int base = 0; base < cnt; base += 64) {
        int k = base + lane;
        int2 ed = make_int2(0, 0);
        if (k < cnt) ed = edata[beg + k];
        int m = min(64, cnt - base);
        int j = 0;
        for (; j + 3 < m; j += 4) {
            int   s0 = __shfl(ed.x, j);     float w0 = __shfl(uif(ed.y), j);
            int   s1 = __shfl(ed.x, j + 1); float w1 = __shfl(uif(ed.y), j + 1);
            int   s2 = __shfl(ed.x, j + 2); float w2 = __shfl(uif(ed.y), j + 2);
            int   s3 = __shfl(ed.x, j + 3); float w3 = __shfl(uif(ed.y), j + 3);
            unsigned h0 = *(const unsigned*)(Ahi + (size_t)s0 * 256 + hoff);
            unsigned h1 = *(const unsigned*)(Ahi + (size_t)s1 * 256 + hoff);
            unsigned h2 = *(const unsigned*)(Ahi + (size_t)s2 * 256 + hoff);
            unsigned h3 = *(const unsigned*)(Ahi + (size_t)s3 * 256 + hoff);
            ax0 = fmaf(w0, uif(h0 << 16), ax0);
            ay0 = fmaf(w0, uif(h0 & 0xffff0000u), ay0);
            ax1 = fmaf(w1, uif(h1 << 16), ax1);
            ay1 = fmaf(w1, uif(h1 & 0xffff0000u), ay1);
            ax2 = fmaf(w2, uif(h2 << 16), ax2);
            ay2 = fmaf(w2, uif(h2 & 0xffff0000u), ay2);
            ax3 = fmaf(w3, uif(h3 << 16), ax3);
            ay3 = fmaf(w3, uif(h3 & 0xffff0000u), ay3);
        }
        for (; j < m; ++j) {
            int   s0 = __shfl(ed.x, j);
            float w0 = __shfl(uif(ed.y), j);
            unsigned h0 = *(const unsigned*)(Ahi + (size_t)s0 * 256 + hoff);
            ax0 = fmaf(w0, uif(h0 << 16), ax0);
            ay0 = fmaf(w0, uif(h0 & 0xffff0000u), ay0);
        }
    }
    float ax = (ax0 + ax1) + (ax2 + ax3);
    float ay = (ay0 + ay1) + (ay2 + ay3);
    unsigned short hx = f2bf(ax), hy = f2bf(ay);
    unsigned short lx = f2bf(ax - bf2f(hx)), ly = f2bf(ay - bf2f(hy));
    *(unsigned*)(Ahi + (size_t)wave * 256 + lane * 2) = ((unsigned)hy << 16) | hx;
    *(unsigned*)(Alo + (size_t)wave * 256 + lane * 2) = ((unsigned)ly << 16) | lx;
}

// ---------------------------------------------------------------------------
// MFMA GEMM: acc = Ahi@Whi + Alo@Whi + Ahi@Wlo over K=256 ([agg|h] concat).
// Block: 64 rows x 128 cols, 4 waves (2x2), wave tile 32x64, 16x16x32 frags.
// W^T staged in 64KB LDS with XOR swizzle (unit ^= col&7); A direct global.
// Epilogue: layer<L-1 -> write h-region hi bf16 (relu); last -> fp32 d_out.
// ---------------------------------------------------------------------------
#define STAGE_W(WSRC)                                                           \
    _Pragma("unroll")                                                           \
    for (int r = 0; r < 16; ++r) {                                              \
        int u = r * 256 + tid;                                                  \
        bf16x8 v = *(const bf16x8*)((WSRC) + (size_t)u * 8);                    \
        int scol = u >> 5, sku = u & 31;                                        \
        *(bf16x8*)((char*)bsh + scol * 512 + ((sku ^ (scol & 7)) << 4)) = v;    \
    }

#define MFMA_PASS(APTR)                                                         \
    _Pragma("unroll")                                                           \
    for (int ks = 0; ks < 8; ++ks) {                                            \
        bf16x8 a0 = *(const bf16x8*)((APTR) + aoff0 + ks * 32 + l4 * 8);        \
        bf16x8 a1 = *(const bf16x8*)((APTR) + aoff1 + ks * 32 + l4 * 8);        \
        _Pragma("unroll")                                                       \
        for (int n = 0; n < 4; ++n) {                                           \
            int col = wc * 64 + n * 16 + l15;                                   \
            int ku = ks * 4 + l4;                                               \
            bf16x8 b = *(const bf16x8*)((const char*)bsh + col * 512            \
                                        + ((ku ^ (col & 7)) << 4));             \
            acc0[n] = __builtin_amdgcn_mfma_f32_16x16x32_bf16(a0, b, acc0[n], 0, 0, 0); \
            acc1[n] = __builtin_amdgcn_mfma_f32_16x16x32_bf16(a1, b, acc1[n], 0, 0, 0); \
        }                                                                       \
    }

__global__ __launch_bounds__(256, 2) void gemm_mfma(
    short* __restrict__ Ahi, short* __restrict__ Alo,
    const short* __restrict__ WhiT, const short* __restrict__ WloT,
    const float* __restrict__ bias, float* __restrict__ outf,
    int N, int relu, int writef)
{
    __shared__ short bsh[32768];   // 64 KB: [128 cols][256 k] bf16, swizzled
    int tid = threadIdx.x;
    int lane = tid & 63;
    int wid = tid >> 6;
    int wr = wid >> 1, wc = wid & 1;
    int l15 = lane & 15, l4 = lane >> 4;
    int row0 = blockIdx.x * 64;

    size_t aoff0 = (size_t)(row0 + wr * 32 + l15) * 256;
    size_t aoff1 = aoff0 + 16 * 256;

    f32x4 acc0[4], acc1[4];
    #pragma unroll
    for (int n = 0; n < 4; ++n) {
        acc0[n] = (f32x4){0.f, 0.f, 0.f, 0.f};
        acc1[n] = (f32x4){0.f, 0.f, 0.f, 0.f};
    }

    STAGE_W(WhiT);
    __syncthreads();
    MFMA_PASS(Ahi);        // A_hi @ W_hi
    MFMA_PASS(Alo);        // A_lo @ W_hi  (h-region of Alo is zero)
    __syncthreads();
    STAGE_W(WloT);
    __syncthreads();
    MFMA_PASS(Ahi);        // A_hi @ W_lo
    __syncthreads();       // all reads of A done before h-region overwrite

    #pragma unroll
    for (int n = 0; n < 4; ++n) {
        int col = wc * 64 + n * 16 + l15;
        float bv = bias[col];
        #pragma unroll
        for (int m = 0; m < 2; ++m) {
            f32x4 a = (m == 0) ? acc0[n] : acc1[n];
            #pragma unroll
            for (int r = 0; r < 4; ++r) {
                int row = row0 + wr * 32 + m * 16 + l4 * 4 + r;
                if (row < N) {
                    float v = a[r] + bv;
                    if (relu) v = fmaxf(v, 0.f);
                    if (writef) {
                        outf[(size_t)row * D + col] = v;
                    } else {
                        Ahi[(size_t)row * 256 + 128 + col] = (short)f2bf(v);
                    }
                }
            }
        }
    }
}

// ---------------------------------------------------------------------------
extern "C" void kernel_launch(void* const* d_in, const int* in_sizes, int n_in,
                              void* d_out, int out_size, void* d_ws, size_t ws_size,
                              hipStream_t stream)
{
    const float* x     = (const float*)d_in[0];
    const int*   ei    = (const int*)d_in[1];
    const float* ew    = (const float*)d_in[2];
    const float* Wrel  = (const float*)d_in[3];
    const float* brel  = (const float*)d_in[4];
    const float* Wroot = (const float*)d_in[5];
    float* out = (float*)d_out;

    int N = in_sizes[0] / D;
    int E = in_sizes[2];
    int L = in_sizes[3] / (D * D);
    int Npad = ((N + 63) / 64) * 64;
    const int* src = ei;
    const int* dst = ei + E;
    int nb = (N + 255) / 256;

    // Workspace layout
    short* Ahi  = (short*)d_ws;                        // Npad*256
    short* Alo  = Ahi + (size_t)Npad * 256;            // Npad*256
    short* WhiT = Alo + (size_t)Npad * 256;            // L*32768
    short* WloT = WhiT + (size_t)L * 32768;            // L*32768
    int2*  edata   = (int2*)(WloT + (size_t)L * 32768);// E int2
    int*   row_ptr = (int*)(edata + E);                // N+1
    int*   cursor  = row_ptr + (N + 1);                // N
    int*   counts  = cursor + N;                       // N
    int*   bsums   = counts + N;                       // nb

    dim3 blk256(256);
    dim3 grdE((E + 255) / 256);
    dim3 grdN(nb);
    dim3 grdGather((N * 64 + 255) / 256);
    dim3 grdGemm(Npad / 64);
    dim3 grdCX((N * 64 + 255) / 256);
    dim3 grdCW((L * 32768 + 255) / 256);

    // --- CSR build (once) ---
    hipMemsetAsync(counts, 0, (size_t)N * sizeof(int), stream);
    hipMemsetAsync(Alo, 0, (size_t)Npad * 256 * sizeof(short), stream);
    hist_kernel<<<grdE, blk256, 0, stream>>>(dst, counts, E);
    blocksum_kernel<<<grdN, blk256, 0, stream>>>(counts, bsums, N);
    scansums_kernel<<<1, blk256, 0, stream>>>(bsums, nb);
    emit_kernel<<<grdN, blk256, 0, stream>>>(counts, bsums, row_ptr, cursor, N, E);
    scatter_csr_kernel<<<grdE, blk256, 0, stream>>>(src, dst, ew, cursor, edata, E);

    // --- hi/lo conversions (once) ---
    convert_w_kernel<<<grdCW, blk256, 0, stream>>>(Wrel, Wroot, WhiT, WloT, L * 32768);
    convert_x_kernel<<<grdCX, blk256, 0, stream>>>(x, Ahi, N);

    // --- layers ---
    for (int l = 0; l < L; ++l) {
        gather_bf16<<<grdGather, blk256, 0, stream>>>(Ahi, Alo, edata, row_ptr, N);
        gemm_mfma<<<grdGemm, blk256, 0, stream>>>(
            Ahi, Alo, WhiT + (size_t)l * 32768, WloT + (size_t)l * 32768,
            brel + (size_t)l * D, out, N, (l < L - 1) ? 1 : 0, (l == L - 1) ? 1 : 0);
    }
}

// Round 7
// 322.528 us; speedup vs baseline: 13.0970x; 1.0300x over previous
//
#include <hip/hip_runtime.h>

#define D 128

typedef __attribute__((ext_vector_type(8))) short bf16x8;
typedef __attribute__((ext_vector_type(4))) float f32x4;

__device__ __forceinline__ float uif(unsigned u) { return __uint_as_float(u); }
__device__ __forceinline__ unsigned short f2bf(float f) {
    unsigned u = __float_as_uint(f);
    u += 0x7fffu + ((u >> 16) & 1u);     // RNE to bf16
    return (unsigned short)(u >> 16);
}
__device__ __forceinline__ float bf2f(unsigned short h) {
    return __uint_as_float(((unsigned)h) << 16);
}

// ---------------------------------------------------------------------------
// CSR build: histogram -> scan (3-kernel) -> position scatter (packed 8B)
// ---------------------------------------------------------------------------
__global__ __launch_bounds__(256) void hist_kernel(
    const int* __restrict__ dst, int* __restrict__ counts, int E)
{
    int e = blockIdx.x * 256 + threadIdx.x;
    if (e < E) atomicAdd(&counts[dst[e]], 1);
}

__global__ __launch_bounds__(256) void blocksum_kernel(
    const int* __restrict__ counts, int* __restrict__ bsums, int N)
{
    __shared__ int red[256];
    int t = threadIdx.x;
    int i = blockIdx.x * 256 + t;
    red[t] = (i < N) ? counts[i] : 0;
    __syncthreads();
    #pragma unroll
    for (int off = 128; off > 0; off >>= 1) {
        if (t < off) red[t] += red[t + off];
        __syncthreads();
    }
    if (t == 0) bsums[blockIdx.x] = red[0];
}

__global__ __launch_bounds__(256) void scansums_kernel(
    int* __restrict__ bsums, int nb)
{
    __shared__ int s[256];
    int t = threadIdx.x;
    int v = (t < nb) ? bsums[t] : 0;
    s[t] = v;
    __syncthreads();
    #pragma unroll
    for (int off = 1; off < 256; off <<= 1) {
        int tmp = (t >= off) ? s[t - off] : 0;
        __syncthreads();
        s[t] += tmp;
        __syncthreads();
    }
    if (t < nb) bsums[t] = s[t] - v;
}

__global__ __launch_bounds__(256) void emit_kernel(
    const int* __restrict__ counts, const int* __restrict__ bsums,
    int* __restrict__ row_ptr, int* __restrict__ cursor, int N, int E)
{
    __shared__ int s[256];
    int t = threadIdx.x;
    int i = blockIdx.x * 256 + t;
    int v = (i < N) ? counts[i] : 0;
    s[t] = v;
    __syncthreads();
    #pragma unroll
    for (int off = 1; off < 256; off <<= 1) {
        int tmp = (t >= off) ? s[t - off] : 0;
        __syncthreads();
        s[t] += tmp;
        __syncthreads();
    }
    int excl = s[t] - v + bsums[blockIdx.x];
    if (i < N) { row_ptr[i] = excl; cursor[i] = excl; }
    if (blockIdx.x == 0 && t == 0) row_ptr[N] = E;
}

__global__ __launch_bounds__(256) void scatter_csr_kernel(
    const int* __restrict__ src, const int* __restrict__ dst,
    const float* __restrict__ ew, int* __restrict__ cursor,
    int2* __restrict__ edata, int E)
{
    int e = blockIdx.x * 256 + threadIdx.x;
    if (e >= E) return;
    int d = dst[e];
    int pos = atomicAdd(&cursor[d], 1);
    edata[pos] = make_int2(src[e], __float_as_int(ew[e]));
}

// ---------------------------------------------------------------------------
// Converts. A layout per plane: [Npad][256] bf16; cols 0-127 = agg (hi+lo),
// cols 128-255 = h (hi only; Alo h-region is zeroed once per call).
// WT layout: [L][128 cols][256 k] bf16; k 0-127 = Wrel rows, 128-255 = Wroot.
// ---------------------------------------------------------------------------
__global__ __launch_bounds__(256) void convert_x_kernel(
    const float* __restrict__ x, short* __restrict__ Ahi, int N)
{
    int t = blockIdx.x * 256 + threadIdx.x;   // over N*64 (pairs of cols)
    if (t >= N * 64) return;
    int row = t >> 6;
    int c2  = (t & 63) * 2;
    float2 v = *(const float2*)(x + (size_t)row * D + c2);
    *(unsigned*)(Ahi + (size_t)row * 256 + 128 + c2) =
        ((unsigned)f2bf(v.y) << 16) | f2bf(v.x);
}

__global__ __launch_bounds__(256) void convert_w_kernel(
    const float* __restrict__ Wrel, const float* __restrict__ Wroot,
    short* __restrict__ WhiT, short* __restrict__ WloT, int total)
{
    int t = blockIdx.x * 256 + threadIdx.x;   // over L*32768
    if (t >= total) return;
    int l = t >> 15;
    int rem = t & 32767;
    int k = rem >> 7;
    int c = rem & 127;
    float f = (k < 128) ? Wrel[(size_t)l * 16384 + k * D + c]
                        : Wroot[(size_t)l * 16384 + (k - 128) * D + c];
    unsigned short h = f2bf(f);
    WhiT[(size_t)l * 32768 + c * 256 + k] = (short)h;
    WloT[(size_t)l * 32768 + c * 256 + k] = (short)f2bf(f - bf2f(h));
}

// ---------------------------------------------------------------------------
// Aggregation: one wave per node, 4 x 16-lane groups. Group g loads edge
// (j+g)'s full 256B row as dwordx4 (16B/lane); lane accumulates 8 cols.
// CONVERGENT inner loop: shuffles unconditional (padding lanes carry w=0,
// src=0 -> accumulate zero). __shfl under divergence = ds_bpermute from
// exec-off lanes = garbage (R6 bug).
// Cross-group fold via shfl_xor(16,32); group 0 writes hi, group 1 writes lo.
// ---------------------------------------------------------------------------
__global__ __launch_bounds__(256) void gather_bf16(
    short* __restrict__ Ahi, short* __restrict__ Alo,
    const int2* __restrict__ edata, const int* __restrict__ row_ptr, int N)
{
    int wave = (blockIdx.x * 256 + threadIdx.x) >> 6;
    int lane = threadIdx.x & 63;
    if (wave >= N) return;
    int g   = lane >> 4;        // group 0..3
    int l16 = lane & 15;        // lane within group
    int beg = row_ptr[wave];
    int cnt = row_ptr[wave + 1] - beg;

    const short* hbase = Ahi + 128 + l16 * 8;   // h-region, this lane's 8 cols

    float acc[8];
    #pragma unroll
    for (int c = 0; c < 8; ++c) acc[c] = 0.f;

    for (int base = 0; base < cnt; base += 64) {
        int k = base + lane;
        int2 ed = make_int2(0, 0);              // w=0, src=0 for padding lanes
        if (k < cnt) ed = edata[beg + k];
        int m = min(64, cnt - base);
        // convergent: j <= 56, so j+4+g <= 63 is always a valid lane; edges
        // past m come from padding lanes (w=0) and contribute nothing.
        for (int j = 0; j < m; j += 8) {
            int   sA = __shfl(ed.x, j + g);
            float wA = __shfl(uif(ed.y), j + g);
            int   sB = __shfl(ed.x, j + 4 + g);
            float wB = __shfl(uif(ed.y), j + 4 + g);
            bf16x8 rA = *(const bf16x8*)(hbase + (size_t)sA * 256);
            bf16x8 rB = *(const bf16x8*)(hbase + (size_t)sB * 256);
            #pragma unroll
            for (int c = 0; c < 8; ++c)
                acc[c] = fmaf(wA, bf2f((unsigned short)rA[c]), acc[c]);
            #pragma unroll
            for (int c = 0; c < 8; ++c)
                acc[c] = fmaf(wB, bf2f((unsigned short)rB[c]), acc[c]);
        }
    }

    // fold the 4 groups (lanes g*16+l16 share cols [l16*8, l16*8+8))
    #pragma unroll
    for (int c = 0; c < 8; ++c) {
        acc[c] += __shfl_xor(acc[c], 16);
        acc[c] += __shfl_xor(acc[c], 32);
    }

    // group 0 -> hi plane, group 1 -> lo plane (16B packed per lane)
    if (g < 2) {
        bf16x8 pk;
        #pragma unroll
        for (int c = 0; c < 8; ++c) {
            unsigned short h = f2bf(acc[c]);
            pk[c] = (g == 0) ? (short)h : (short)f2bf(acc[c] - bf2f(h));
        }
        short* dstp = (g == 0 ? Ahi : Alo) + (size_t)wave * 256 + l16 * 8;
        *(bf16x8*)dstp = pk;
    }
}

// ---------------------------------------------------------------------------
// MFMA GEMM: acc = Ahi@Whi + Alo@Whi + Ahi@Wlo over K=256 ([agg|h] concat).
// Block: 64 rows x 128 cols, 4 waves (2x2), wave tile 32x64, 16x16x32 frags.
// W^T staged in 64KB LDS with XOR swizzle (unit ^= col&7); A direct global.
// Epilogue: layer<L-1 -> write h-region hi bf16 (relu); last -> fp32 d_out.
// ---------------------------------------------------------------------------
#define STAGE_W(WSRC)                                                           \
    _Pragma("unroll")                                                           \
    for (int r = 0; r < 16; ++r) {                                              \
        int u = r * 256 + tid;                                                  \
        bf16x8 v = *(const bf16x8*)((WSRC) + (size_t)u * 8);                    \
        int scol = u >> 5, sku = u & 31;                                        \
        *(bf16x8*)((char*)bsh + scol * 512 + ((sku ^ (scol & 7)) << 4)) = v;    \
    }

#define MFMA_PASS(APTR)                                                         \
    _Pragma("unroll")                                                           \
    for (int ks = 0; ks < 8; ++ks) {                                            \
        bf16x8 a0 = *(const bf16x8*)((APTR) + aoff0 + ks * 32 + l4 * 8);        \
        bf16x8 a1 = *(const bf16x8*)((APTR) + aoff1 + ks * 32 + l4 * 8);        \
        _Pragma("unroll")                                                       \
        for (int n = 0; n < 4; ++n) {                                           \
            int col = wc * 64 + n * 16 + l15;                                   \
            int ku = ks * 4 + l4;                                               \
            bf16x8 b = *(const bf16x8*)((const char*)bsh + col * 512            \
                                        + ((ku ^ (col & 7)) << 4));             \
            acc0[n] = __builtin_amdgcn_mfma_f32_16x16x32_bf16(a0, b, acc0[n], 0, 0, 0); \
            acc1[n] = __builtin_amdgcn_mfma_f32_16x16x32_bf16(a1, b, acc1[n], 0, 0, 0); \
        }                                                                       \
    }

__global__ __launch_bounds__(256, 2) void gemm_mfma(
    short* __restrict__ Ahi, short* __restrict__ Alo,
    const short* __restrict__ WhiT, const short* __restrict__ WloT,
    const float* __restrict__ bias, float* __restrict__ outf,
    int N, int relu, int writef)
{
    __shared__ short bsh[32768];   // 64 KB: [128 cols][256 k] bf16, swizzled
    int tid = threadIdx.x;
    int lane = tid & 63;
    int wid = tid >> 6;
    int wr = wid >> 1, wc = wid & 1;
    int l15 = lane & 15, l4 = lane >> 4;
    int row0 = blockIdx.x * 64;

    size_t aoff0 = (size_t)(row0 + wr * 32 + l15) * 256;
    size_t aoff1 = aoff0 + 16 * 256;

    f32x4 acc0[4], acc1[4];
    #pragma unroll
    for (int n = 0; n < 4; ++n) {
        acc0[n] = (f32x4){0.f, 0.f, 0.f, 0.f};
        acc1[n] = (f32x4){0.f, 0.f, 0.f, 0.f};
    }

    STAGE_W(WhiT);
    __syncthreads();
    MFMA_PASS(Ahi);        // A_hi @ W_hi
    MFMA_PASS(Alo);        // A_lo @ W_hi  (h-region of Alo is zero)
    __syncthreads();
    STAGE_W(WloT);
    __syncthreads();
    MFMA_PASS(Ahi);        // A_hi @ W_lo
    __syncthreads();       // all reads of A done before h-region overwrite

    #pragma unroll
    for (int n = 0; n < 4; ++n) {
        int col = wc * 64 + n * 16 + l15;
        float bv = bias[col];
        #pragma unroll
        for (int m = 0; m < 2; ++m) {
            f32x4 a = (m == 0) ? acc0[n] : acc1[n];
            #pragma unroll
            for (int r = 0; r < 4; ++r) {
                int row = row0 + wr * 32 + m * 16 + l4 * 4 + r;
                if (row < N) {
                    float v = a[r] + bv;
                    if (relu) v = fmaxf(v, 0.f);
                    if (writef) {
                        outf[(size_t)row * D + col] = v;
                    } else {
                        Ahi[(size_t)row * 256 + 128 + col] = (short)f2bf(v);
                    }
                }
            }
        }
    }
}

// ---------------------------------------------------------------------------
extern "C" void kernel_launch(void* const* d_in, const int* in_sizes, int n_in,
                              void* d_out, int out_size, void* d_ws, size_t ws_size,
                              hipStream_t stream)
{
    const float* x     = (const float*)d_in[0];
    const int*   ei    = (const int*)d_in[1];
    const float* ew    = (const float*)d_in[2];
    const float* Wrel  = (const float*)d_in[3];
    const float* brel  = (const float*)d_in[4];
    const float* Wroot = (const float*)d_in[5];
    float* out = (float*)d_out;

    int N = in_sizes[0] / D;
    int E = in_sizes[2];
    int L = in_sizes[3] / (D * D);
    int Npad = ((N + 63) / 64) * 64;
    const int* src = ei;
    const int* dst = ei + E;
    int nb = (N + 255) / 256;

    // Workspace layout
    short* Ahi  = (short*)d_ws;                        // Npad*256
    short* Alo  = Ahi + (size_t)Npad * 256;            // Npad*256
    short* WhiT = Alo + (size_t)Npad * 256;            // L*32768
    short* WloT = WhiT + (size_t)L * 32768;            // L*32768
    int2*  edata   = (int2*)(WloT + (size_t)L * 32768);// E int2
    int*   row_ptr = (int*)(edata + E);                // N+1
    int*   cursor  = row_ptr + (N + 1);                // N
    int*   counts  = cursor + N;                       // N
    int*   bsums   = counts + N;                       // nb

    dim3 blk256(256);
    dim3 grdE((E + 255) / 256);
    dim3 grdN(nb);
    dim3 grdGather((N * 64 + 255) / 256);
    dim3 grdGemm(Npad / 64);
    dim3 grdCX((N * 64 + 255) / 256);
    dim3 grdCW((L * 32768 + 255) / 256);

    // --- CSR build (once) ---
    hipMemsetAsync(counts, 0, (size_t)N * sizeof(int), stream);
    hipMemsetAsync(Alo, 0, (size_t)Npad * 256 * sizeof(short), stream);
    hist_kernel<<<grdE, blk256, 0, stream>>>(dst, counts, E);
    blocksum_kernel<<<grdN, blk256, 0, stream>>>(counts, bsums, N);
    scansums_kernel<<<1, blk256, 0, stream>>>(bsums, nb);
    emit_kernel<<<grdN, blk256, 0, stream>>>(counts, bsums, row_ptr, cursor, N, E);
    scatter_csr_kernel<<<grdE, blk256, 0, stream>>>(src, dst, ew, cursor, edata, E);

    // --- hi/lo conversions (once) ---
    convert_w_kernel<<<grdCW, blk256, 0, stream>>>(Wrel, Wroot, WhiT, WloT, L * 32768);
    convert_x_kernel<<<grdCX, blk256, 0, stream>>>(x, Ahi, N);

    // --- layers ---
    for (int l = 0; l < L; ++l) {
        gather_bf16<<<grdGather, blk256, 0, stream>>>(Ahi, Alo, edata, row_ptr, N);
        gemm_mfma<<<grdGemm, blk256, 0, stream>>>(
            Ahi, Alo, WhiT + (size_t)l * 32768, WloT + (size_t)l * 32768,
            brel + (size_t)l * D, out, N, (l < L - 1) ? 1 : 0, (l == L - 1) ? 1 : 0);
    }
}

// Round 8
// 297.053 us; speedup vs baseline: 14.2202x; 1.0858x over previous
//
#include <hip/hip_runtime.h>

#define D 128
#define SC_IT 16   // edges per thread in scatter chunk

typedef __attribute__((ext_vector_type(8))) short bf16x8;
typedef __attribute__((ext_vector_type(4))) float f32x4;

__device__ __forceinline__ float uif(unsigned u) { return __uint_as_float(u); }
__device__ __forceinline__ unsigned short f2bf(float f) {
    unsigned u = __float_as_uint(f);
    u += 0x7fffu + ((u >> 16) & 1u);     // RNE to bf16
    return (unsigned short)(u >> 16);
}
__device__ __forceinline__ float bf2f(unsigned short h) {
    return __uint_as_float(((unsigned)h) << 16);
}

// ---------------------------------------------------------------------------
// CSR build: histogram -> scan (3-kernel) -> XCD-partitioned position scatter
// ---------------------------------------------------------------------------
__global__ __launch_bounds__(256) void hist_kernel(
    const int* __restrict__ dst, int* __restrict__ counts, int E)
{
    int e = blockIdx.x * 256 + threadIdx.x;
    if (e < E) atomicAdd(&counts[dst[e]], 1);
}

__global__ __launch_bounds__(256) void blocksum_kernel(
    const int* __restrict__ counts, int* __restrict__ bsums, int N)
{
    __shared__ int red[256];
    int t = threadIdx.x;
    int i = blockIdx.x * 256 + t;
    red[t] = (i < N) ? counts[i] : 0;
    __syncthreads();
    #pragma unroll
    for (int off = 128; off > 0; off >>= 1) {
        if (t < off) red[t] += red[t + off];
        __syncthreads();
    }
    if (t == 0) bsums[blockIdx.x] = red[0];
}

__global__ __launch_bounds__(256) void scansums_kernel(
    int* __restrict__ bsums, int nb)
{
    __shared__ int s[256];
    int t = threadIdx.x;
    int v = (t < nb) ? bsums[t] : 0;
    s[t] = v;
    __syncthreads();
    #pragma unroll
    for (int off = 1; off < 256; off <<= 1) {
        int tmp = (t >= off) ? s[t - off] : 0;
        __syncthreads();
        s[t] += tmp;
        __syncthreads();
    }
    if (t < nb) bsums[t] = s[t] - v;
}

__global__ __launch_bounds__(256) void emit_kernel(
    const int* __restrict__ counts, const int* __restrict__ bsums,
    int* __restrict__ row_ptr, int* __restrict__ cursor, int N, int E)
{
    __shared__ int s[256];
    int t = threadIdx.x;
    int i = blockIdx.x * 256 + t;
    int v = (i < N) ? counts[i] : 0;
    s[t] = v;
    __syncthreads();
    #pragma unroll
    for (int off = 1; off < 256; off <<= 1) {
        int tmp = (t >= off) ? s[t - off] : 0;
        __syncthreads();
        s[t] += tmp;
        __syncthreads();
    }
    int excl = s[t] - v + bsums[blockIdx.x];
    if (i < N) { row_ptr[i] = excl; cursor[i] = excl; }
    if (blockIdx.x == 0 && t == 0) row_ptr[N] = E;
}

// XCD-partitioned scatter: xcd = blockIdx&7 owns dst range [xcd*N/8,(xcd+1)*N/8).
// All writers of a CSR line sit on one XCD -> partial 8B stores merge in its
// L2 and evict as full lines (perf heuristic only; correct for any mapping).
__global__ __launch_bounds__(256) void scatter_xcd_kernel(
    const int* __restrict__ src, const int* __restrict__ dst,
    const float* __restrict__ ew, int* __restrict__ cursor,
    int2* __restrict__ edata, int E, int N)
{
    int xcd   = blockIdx.x & 7;
    int chunk = blockIdx.x >> 3;
    int lo = (int)(((long long)xcd * N) >> 3);
    int hi = (int)(((long long)(xcd + 1) * N) >> 3);
    int base = chunk * (256 * SC_IT) + threadIdx.x;
    #pragma unroll
    for (int it = 0; it < SC_IT; ++it) {
        int e = base + it * 256;
        if (e < E) {
            int d = __builtin_nontemporal_load(&dst[e]);
            if (d >= lo && d < hi) {
                int pos = atomicAdd(&cursor[d], 1);
                int s = __builtin_nontemporal_load(&src[e]);
                float w = __builtin_nontemporal_load(&ew[e]);
                edata[pos] = make_int2(s, __float_as_int(w));
            }
        }
    }
}

// ---------------------------------------------------------------------------
// Converts. A layout per plane: [Npad][256] bf16; cols 0-127 = agg (hi+lo),
// cols 128-255 = h (hi only; Alo h-region is never read).
// WT layout: [L][128 cols][256 k] bf16; k 0-127 = Wrel rows, 128-255 = Wroot.
// ---------------------------------------------------------------------------
__global__ __launch_bounds__(256) void convert_x_kernel(
    const float* __restrict__ x, short* __restrict__ Ahi, int N)
{
    int t = blockIdx.x * 256 + threadIdx.x;   // over N*64 (pairs of cols)
    if (t >= N * 64) return;
    int row = t >> 6;
    int c2  = (t & 63) * 2;
    float2 v = *(const float2*)(x + (size_t)row * D + c2);
    *(unsigned*)(Ahi + (size_t)row * 256 + 128 + c2) =
        ((unsigned)f2bf(v.y) << 16) | f2bf(v.x);
}

__global__ __launch_bounds__(256) void convert_w_kernel(
    const float* __restrict__ Wrel, const float* __restrict__ Wroot,
    short* __restrict__ WhiT, short* __restrict__ WloT, int total)
{
    int t = blockIdx.x * 256 + threadIdx.x;   // over L*32768
    if (t >= total) return;
    int l = t >> 15;
    int rem = t & 32767;
    int k = rem >> 7;
    int c = rem & 127;
    float f = (k < 128) ? Wrel[(size_t)l * 16384 + k * D + c]
                        : Wroot[(size_t)l * 16384 + (k - 128) * D + c];
    unsigned short h = f2bf(f);
    WhiT[(size_t)l * 32768 + c * 256 + k] = (short)h;
    WloT[(size_t)l * 32768 + c * 256 + k] = (short)f2bf(f - bf2f(h));
}

// ---------------------------------------------------------------------------
// Aggregation: one wave per node, 4 x 16-lane groups. Group g loads edge
// (j+g)'s full 256B row as dwordx4 (16B/lane); lane accumulates 8 cols.
// CONVERGENT inner loop (R6 lesson: __shfl under divergence = garbage).
// Cross-group fold via shfl_xor(16,32); group 0 writes hi, group 1 writes lo.
// ---------------------------------------------------------------------------
__global__ __launch_bounds__(256) void gather_bf16(
    short* __restrict__ Ahi, short* __restrict__ Alo,
    const int2* __restrict__ edata, const int* __restrict__ row_ptr, int N)
{
    int wave = (blockIdx.x * 256 + threadIdx.x) >> 6;
    int lane = threadIdx.x & 63;
    if (wave >= N) return;
    int g   = lane >> 4;        // group 0..3
    int l16 = lane & 15;        // lane within group
    int beg = row_ptr[wave];
    int cnt = row_ptr[wave + 1] - beg;

    const short* hbase = Ahi + 128 + l16 * 8;   // h-region, this lane's 8 cols

    float acc[8];
    #pragma unroll
    for (int c = 0; c < 8; ++c) acc[c] = 0.f;

    for (int base = 0; base < cnt; base += 64) {
        int k = base + lane;
        int2 ed = make_int2(0, 0);              // w=0, src=0 for padding lanes
        if (k < cnt) ed = edata[beg + k];
        int m = min(64, cnt - base);
        for (int j = 0; j < m; j += 8) {
            int   sA = __shfl(ed.x, j + g);
            float wA = __shfl(uif(ed.y), j + g);
            int   sB = __shfl(ed.x, j + 4 + g);
            float wB = __shfl(uif(ed.y), j + 4 + g);
            bf16x8 rA = *(const bf16x8*)(hbase + (size_t)sA * 256);
            bf16x8 rB = *(const bf16x8*)(hbase + (size_t)sB * 256);
            #pragma unroll
            for (int c = 0; c < 8; ++c)
                acc[c] = fmaf(wA, bf2f((unsigned short)rA[c]), acc[c]);
            #pragma unroll
            for (int c = 0; c < 8; ++c)
                acc[c] = fmaf(wB, bf2f((unsigned short)rB[c]), acc[c]);
        }
    }

    #pragma unroll
    for (int c = 0; c < 8; ++c) {
        acc[c] += __shfl_xor(acc[c], 16);
        acc[c] += __shfl_xor(acc[c], 32);
    }

    if (g < 2) {
        bf16x8 pk;
        #pragma unroll
        for (int c = 0; c < 8; ++c) {
            unsigned short h = f2bf(acc[c]);
            pk[c] = (g == 0) ? (short)h : (short)f2bf(acc[c] - bf2f(h));
        }
        short* dstp = (g == 0 ? Ahi : Alo) + (size_t)wave * 256 + l16 * 8;
        *(bf16x8*)dstp = pk;
    }
}

// ---------------------------------------------------------------------------
// MFMA GEMM: acc = Ahi@Whi (K=256) + Alo@Whi (K=128, agg only) + Ahi@Wlo (K=256).
// Block: 64 rows x 128 cols, 4 waves (2x2), wave tile 32x64, 16x16x32 frags.
// W^T staged in 64KB LDS with XOR swizzle (unit ^= col&7); A direct global.
// Epilogue: layer<L-1 -> write h-region hi bf16 (relu); last -> fp32 d_out.
// ---------------------------------------------------------------------------
#define STAGE_W(WSRC)                                                           \
    _Pragma("unroll")                                                           \
    for (int r = 0; r < 16; ++r) {                                              \
        int u = r * 256 + tid;                                                  \
        bf16x8 v = *(const bf16x8*)((WSRC) + (size_t)u * 8);                    \
        int scol = u >> 5, sku = u & 31;                                        \
        *(bf16x8*)((char*)bsh + scol * 512 + ((sku ^ (scol & 7)) << 4)) = v;    \
    }

#define MFMA_PASS(APTR, KSN)                                                    \
    _Pragma("unroll")                                                           \
    for (int ks = 0; ks < (KSN); ++ks) {                                        \
        bf16x8 a0 = *(const bf16x8*)((APTR) + aoff0 + ks * 32 + l4 * 8);        \
        bf16x8 a1 = *(const bf16x8*)((APTR) + aoff1 + ks * 32 + l4 * 8);        \
        _Pragma("unroll")                                                       \
        for (int n = 0; n < 4; ++n) {                                           \
            int col = wc * 64 + n * 16 + l15;                                   \
            int ku = ks * 4 + l4;                                               \
            bf16x8 b = *(const bf16x8*)((const char*)bsh + col * 512            \
                                        + ((ku ^ (col & 7)) << 4));             \
            acc0[n] = __builtin_amdgcn_mfma_f32_16x16x32_bf16(a0, b, acc0[n], 0, 0, 0); \
            acc1[n] = __builtin_amdgcn_mfma_f32_16x16x32_bf16(a1, b, acc1[n], 0, 0, 0); \
        }                                                                       \
    }

__global__ __launch_bounds__(256, 2) void gemm_mfma(
    short* __restrict__ Ahi, short* __restrict__ Alo,
    const short* __restrict__ WhiT, const short* __restrict__ WloT,
    const float* __restrict__ bias, float* __restrict__ outf,
    int N, int relu, int writef)
{
    __shared__ short bsh[32768];   // 64 KB: [128 cols][256 k] bf16, swizzled
    int tid = threadIdx.x;
    int lane = tid & 63;
    int wid = tid >> 6;
    int wr = wid >> 1, wc = wid & 1;
    int l15 = lane & 15, l4 = lane >> 4;
    int row0 = blockIdx.x * 64;

    size_t aoff0 = (size_t)(row0 + wr * 32 + l15) * 256;
    size_t aoff1 = aoff0 + 16 * 256;

    f32x4 acc0[4], acc1[4];
    #pragma unroll
    for (int n = 0; n < 4; ++n) {
        acc0[n] = (f32x4){0.f, 0.f, 0.f, 0.f};
        acc1[n] = (f32x4){0.f, 0.f, 0.f, 0.f};
    }

    STAGE_W(WhiT);
    __syncthreads();
    MFMA_PASS(Ahi, 8);     // A_hi @ W_hi, K=256
    MFMA_PASS(Alo, 4);     // A_lo @ W_hi, K=128 (agg region only; h-lo == 0)
    __syncthreads();
    STAGE_W(WloT);
    __syncthreads();
    MFMA_PASS(Ahi, 8);     // A_hi @ W_lo, K=256
    __syncthreads();       // all reads of A done before h-region overwrite

    #pragma unroll
    for (int n = 0; n < 4; ++n) {
        int col = wc * 64 + n * 16 + l15;
        float bv = bias[col];
        #pragma unroll
        for (int m = 0; m < 2; ++m) {
            f32x4 a = (m == 0) ? acc0[n] : acc1[n];
            #pragma unroll
            for (int r = 0; r < 4; ++r) {
                int row = row0 + wr * 32 + m * 16 + l4 * 4 + r;
                if (row < N) {
                    float v = a[r] + bv;
                    if (relu) v = fmaxf(v, 0.f);
                    if (writef) {
                        outf[(size_t)row * D + col] = v;
                    } else {
                        Ahi[(size_t)row * 256 + 128 + col] = (short)f2bf(v);
                    }
                }
            }
        }
    }
}

// ---------------------------------------------------------------------------
extern "C" void kernel_launch(void* const* d_in, const int* in_sizes, int n_in,
                              void* d_out, int out_size, void* d_ws, size_t ws_size,
                              hipStream_t stream)
{
    const float* x     = (const float*)d_in[0];
    const int*   ei    = (const int*)d_in[1];
    const float* ew    = (const float*)d_in[2];
    const float* Wrel  = (const float*)d_in[3];
    const float* brel  = (const float*)d_in[4];
    const float* Wroot = (const float*)d_in[5];
    float* out = (float*)d_out;

    int N = in_sizes[0] / D;
    int E = in_sizes[2];
    int L = in_sizes[3] / (D * D);
    int Npad = ((N + 63) / 64) * 64;
    const int* src = ei;
    const int* dst = ei + E;
    int nb = (N + 255) / 256;

    // Workspace layout
    short* Ahi  = (short*)d_ws;                        // Npad*256
    short* Alo  = Ahi + (size_t)Npad * 256;            // Npad*256
    short* WhiT = Alo + (size_t)Npad * 256;            // L*32768
    short* WloT = WhiT + (size_t)L * 32768;            // L*32768
    int2*  edata   = (int2*)(WloT + (size_t)L * 32768);// E int2
    int*   row_ptr = (int*)(edata + E);                // N+1
    int*   cursor  = row_ptr + (N + 1);                // N
    int*   counts  = cursor + N;                       // N
    int*   bsums   = counts + N;                       // nb

    dim3 blk256(256);
    dim3 grdE((E + 255) / 256);
    dim3 grdN(nb);
    int nchunks = (E + 256 * SC_IT - 1) / (256 * SC_IT);
    dim3 grdScat(nchunks * 8);
    dim3 grdGather((N * 64 + 255) / 256);
    dim3 grdGemm(Npad / 64);
    dim3 grdCX((N * 64 + 255) / 256);
    dim3 grdCW((L * 32768 + 255) / 256);

    // --- CSR build (once) ---
    hipMemsetAsync(counts, 0, (size_t)N * sizeof(int), stream);
    hist_kernel<<<grdE, blk256, 0, stream>>>(dst, counts, E);
    blocksum_kernel<<<grdN, blk256, 0, stream>>>(counts, bsums, N);
    scansums_kernel<<<1, blk256, 0, stream>>>(bsums, nb);
    emit_kernel<<<grdN, blk256, 0, stream>>>(counts, bsums, row_ptr, cursor, N, E);
    scatter_xcd_kernel<<<grdScat, blk256, 0, stream>>>(src, dst, ew, cursor, edata, E, N);

    // --- hi/lo conversions (once) ---
    convert_w_kernel<<<grdCW, blk256, 0, stream>>>(Wrel, Wroot, WhiT, WloT, L * 32768);
    convert_x_kernel<<<grdCX, blk256, 0, stream>>>(x, Ahi, N);

    // --- layers ---
    for (int l = 0; l < L; ++l) {
        gather_bf16<<<grdGather, blk256, 0, stream>>>(Ahi, Alo, edata, row_ptr, N);
        gemm_mfma<<<grdGemm, blk256, 0, stream>>>(
            Ahi, Alo, WhiT + (size_t)l * 32768, WloT + (size_t)l * 32768,
            brel + (size_t)l * D, out, N, (l < L - 1) ? 1 : 0, (l == L - 1) ? 1 : 0);
    }
}